// Round 4
// baseline (478.303 us; speedup 1.0000x reference)
//
#include <hip/hip_runtime.h>
#include <cstdint>

using u16 = unsigned short;
using f16 = _Float16;

// Problem constants
static constexpr int N = 716;
static constexpr int T = 12;
static constexpr int C = 10;
static constexpr int B = 64;
static constexpr int E = 11441;

static constexpr int KP = 768;           // padded contraction dim (multiple of 64)
static constexpr int BK = 64;            // K-step
static constexpr int NSTEP = KP / BK;    // 12

typedef __attribute__((ext_vector_type(8))) f16 f16x8;
typedef __attribute__((ext_vector_type(4))) float f32x4;

__device__ __forceinline__ int node_off(int n) {
    int q = n / 17, r = n % 17;
    return 8 * n + 136 * q + (r * (r - 1)) / 2;
}

typedef const __attribute__((address_space(1))) unsigned int* gp1_t;
typedef __attribute__((address_space(3))) unsigned int* lp3_t;
__device__ __forceinline__ void gload16(const void* g, void* l) {
    __builtin_amdgcn_global_load_lds((gp1_t)g, (lp3_t)l, 16, 0, 0);
}

__device__ __forceinline__ float wsum(float p) {
#pragma unroll
    for (int o = 1; o < 64; o <<= 1) p += __shfl_xor(p, o);
    return p;
}

// ---------------- K1: static preprocessing of Vs/bs (branched grid) ----------------
// blocks [0,2148): AH/AL f16 hi/lo planes of Vs, [716][768] zero-padded
// blocks [2148,4151): bsT[j][i] = bs[i][j]
// blocks [4151,4867): rs[n] = sum_i Vs[n][i]
static constexpr int KB_PLANES = (N * KP) / 256;          // 2148 exact
static constexpr int KB_BST    = (N * N + 255) / 256;     // 2003
static constexpr int KB_RS     = N;                        // 716

__global__ void __launch_bounds__(256) k_static(const float* __restrict__ Vs,
                                                const float* __restrict__ bs,
                                                f16* __restrict__ AH, f16* __restrict__ AL,
                                                float* __restrict__ bsT, float* __restrict__ rs) {
    int blk = blockIdx.x;
    if (blk < KB_PLANES) {
        int idx = blk * 256 + threadIdx.x;
        int n = idx / KP, ic = idx - n * KP;
        float v = (ic < N) ? Vs[(size_t)n * N + ic] : 0.f;
        f16 hi = (f16)v;
        AH[idx] = hi;
        AL[idx] = (f16)(v - (float)hi);
    } else if (blk < KB_PLANES + KB_BST) {
        int idx = (blk - KB_PLANES) * 256 + threadIdx.x;
        if (idx < N * N) {
            int j = idx / N, i = idx - j * N;
            bsT[(size_t)j * N + i] = bs[(size_t)i * N + j];
        }
    } else {
        int n = blk - (KB_PLANES + KB_BST);
        float s = 0.f;
        for (int i = threadIdx.x; i < N; i += 256) s += Vs[(size_t)n * N + i];
#pragma unroll
        for (int o = 32; o >= 1; o >>= 1) s += __shfl_xor(s, o);
        __shared__ float red[4];
        if ((threadIdx.x & 63) == 0) red[threadIdx.x >> 6] = s;
        __syncthreads();
        if (threadIdx.x == 0) rs[n] = red[0] + red[1] + red[2] + red[3];
    }
}

// ---------------- K2: fully-fused ragged linear chain, one WAVE per (b,n) ----------
// Computes (in-register): wv,bb, u[e], then rhs[b,n,:] and lhs[b,n,:].
__global__ void __launch_bounds__(256) k_fused_ln(const float* __restrict__ vals,
                                                  const float* __restrict__ W_flat,
                                                  const float* __restrict__ bias,
                                                  const float* __restrict__ W1,
                                                  const float* __restrict__ W2,
                                                  const float* __restrict__ W3,
                                                  float* __restrict__ rhs,
                                                  float* __restrict__ lhs) {
    int wid = blockIdx.x * 4 + (threadIdx.x >> 6);   // 0 .. B*N-1 (exact grid)
    int lane = threadIdx.x & 63;
    int b = wid / N, n = wid - b * N;
    int off = node_off(n);
    int deg = 8 + (n % 17);
    bool act = lane < deg;

    float w1[T];
    float S1 = 0.f;
#pragma unroll
    for (int t = 0; t < T; ++t) { w1[t] = W1[t]; S1 += w1[t]; }

    // wv for this lane's neighbor slot
    float wv = 0.f;
#pragma unroll
    for (int c = 0; c < C; ++c)
        wv += W3[c] * (act ? W_flat[(size_t)c * E + off + lane] : 0.f);

    // bb[n] (wave-uniform, broadcast loads)
    float bbv = 0.f;
#pragma unroll
    for (int c = 0; c < C; ++c) bbv += W3[c] * bias[n * C + c];

    // single pass over vals: u (lane-local) and rhs_t (wave reduction)
    float u = 0.f;
    float rloc[T];
#pragma unroll
    for (int t = 0; t < T; ++t) {
        float v = act ? vals[((size_t)b * T + t) * E + off + lane] : 0.f;
        u = fmaf(v, w1[t], u);
        rloc[t] = wsum(v * wv) + bbv;
    }

    // a[c] (wave-uniform after reduce) folded straight into lhs
    float lh[T];
#pragma unroll
    for (int t = 0; t < T; ++t) lh[t] = 0.f;
#pragma unroll
    for (int c = 0; c < C; ++c) {
        float p = act ? u * W_flat[(size_t)c * E + off + lane] : 0.f;
        float ac = wsum(p) + S1 * bias[n * C + c];
#pragma unroll
        for (int t = 0; t < T; ++t) lh[t] = fmaf(ac, W2[c * T + t], lh[t]);
    }

    // lane t writes element t (compile-time indexed extraction, no scratch)
    float outv_r = 0.f, outv_l = 0.f;
#pragma unroll
    for (int t = 0; t < T; ++t)
        if (lane == t) { outv_r = rloc[t]; outv_l = lh[t]; }
    if (lane < T) {
        size_t base = ((size_t)b * N + n) * T + lane;
        rhs[base] = outv_r;
        lhs[base] = outv_l;
    }
}

// ---------------- sigT plane: T16[b][j][i] = sigmoid(dot(lhs[i],rhs[j]) + bs[i][j]) - 0.5
__global__ void __launch_bounds__(256) k_prod2(const float* __restrict__ lhs,
                                               const float* __restrict__ rhs,
                                               const float* __restrict__ bsT,
                                               f16* __restrict__ T16) {
    __shared__ float rl[16][12];
    int tid = threadIdx.x;
    int b = blockIdx.z;
    int j0 = blockIdx.y * 16;
    int i = blockIdx.x * 256 + tid;     // 0..767
    if (tid < 192) {
        int jj = tid / 12, t = tid - jj * 12;
        int j = j0 + jj;
        rl[jj][t] = (j < N) ? rhs[((size_t)b * N + j) * T + t] : 0.f;
    }
    __syncthreads();
    float l[12];
    bool live = (i < N);
    if (live) {
        const float4* lp = (const float4*)(lhs + ((size_t)b * N + i) * T);
        float4 a0 = lp[0], a1 = lp[1], a2 = lp[2];
        l[0] = a0.x; l[1] = a0.y; l[2] = a0.z; l[3] = a0.w;
        l[4] = a1.x; l[5] = a1.y; l[6] = a1.z; l[7] = a1.w;
        l[8] = a2.x; l[9] = a2.y; l[10] = a2.z; l[11] = a2.w;
    }
#pragma unroll
    for (int jj = 0; jj < 16; ++jj) {
        int j = j0 + jj;
        if (j >= N) break;
        size_t dst = ((size_t)b * N + j) * KP + i;
        if (live) {
            float s = bsT[(size_t)j * N + i];
#pragma unroll
            for (int t = 0; t < T; ++t) s = fmaf(l[t], rl[jj][t], s);
            float v = 1.f / (1.f + __expf(-s)) - 0.5f;
            T16[dst] = (f16)v;
        } else {
            T16[dst] = (f16)0.f;
        }
    }
}

// ---------------- split-f16 MFMA GEMM + fused partial softmax stats --------------
// S[b][n][j] = sum_i Vs[n][i]*sigc[b][i][j] + 0.5*rs[n]
// (unchanged from round 3 — validated)
__global__ void __launch_bounds__(256, 3)
k_mfma(const f16* __restrict__ AH, const f16* __restrict__ AL,
       const f16* __restrict__ Bp, const float* __restrict__ rs,
       float* __restrict__ S, float* __restrict__ pmax, float* __restrict__ psum) {
    __shared__ f16 lds[3][128 * BK];    // 3 planes x 16 KB = 48 KB
    __shared__ float smx[2][2][64];
    __shared__ float ssm[2][2][64];
    const int tid = threadIdx.x;
    const int bz = blockIdx.z;
    const int nt = blockIdx.y, jt = blockIdx.x;
    const int n0 = nt * 128, j0 = jt * 128;
    const int lane = tid & 63;
    const int wid = tid >> 6;
    const int wr = wid >> 1, wc = wid & 1;
    const int r = lane & 15, h = lane >> 4;

    const f16* srcB = Bp + (size_t)bz * N * KP;

    const int cb_sw = ((tid & 7) * 16) ^ (((tid >> 3) & 7) * 16);
    const int row_base = tid >> 3;

    f32x4 acc[4][4] = {};

    for (int step = 0; step < NSTEP; ++step) {
        const int mb = step * (BK * 2);   // byte offset along a row
#pragma unroll
        for (int p = 0; p < 3; ++p) {
            const int rbase = (p < 2) ? n0 : j0;
            const f16* src = (p == 0) ? AH : (p == 1) ? AL : srcB;
#pragma unroll
            for (int q = 0; q < 4; ++q) {
                int lrow = q * 32 + row_base;
                int grow = rbase + lrow;
                if (grow > N - 1) grow = N - 1;   // clamp: harmless data, outputs masked
                const char* g = (const char*)src + (size_t)grow * (KP * 2) + mb + cb_sw;
                gload16(g, (char*)&lds[p][0] + q * 4096 + tid * 16);
            }
        }
        __syncthreads();
#pragma unroll
        for (int kk = 0; kk < 2; ++kk) {
            f16x8 aHf[4], aLf[4], bf[4];
#pragma unroll
            for (int f = 0; f < 4; ++f) {
                int arow = wr * 64 + f * 16 + r;
                int aidx = arow * BK + ((kk * 32 + h * 8) ^ ((arow & 7) * 8));
                aHf[f] = *(const f16x8*)&lds[0][aidx];
                aLf[f] = *(const f16x8*)&lds[1][aidx];
                int brow = wc * 64 + f * 16 + r;
                int bidx = brow * BK + ((kk * 32 + h * 8) ^ ((brow & 7) * 8));
                bf[f] = *(const f16x8*)&lds[2][bidx];
            }
#pragma unroll
            for (int fi = 0; fi < 4; ++fi)
#pragma unroll
                for (int fj = 0; fj < 4; ++fj) {
                    acc[fi][fj] = __builtin_amdgcn_mfma_f32_16x16x32_f16(aHf[fi], bf[fj], acc[fi][fj], 0, 0, 0);
                    acc[fi][fj] = __builtin_amdgcn_mfma_f32_16x16x32_f16(aLf[fi], bf[fj], acc[fi][fj], 0, 0, 0);
                }
        }
        __syncthreads();
    }

    // epilogue: add 0.5*rowsum term, write S, fused per-column partial stats
    float rsv[4][4];
#pragma unroll
    for (int fi = 0; fi < 4; ++fi)
#pragma unroll
        for (int qq = 0; qq < 4; ++qq) {
            int rg = n0 + wr * 64 + fi * 16 + h * 4 + qq;
            rsv[fi][qq] = (rg < N) ? 0.5f * rs[rg] : 0.f;
        }
#pragma unroll
    for (int fi = 0; fi < 4; ++fi)
#pragma unroll
        for (int fj = 0; fj < 4; ++fj)
#pragma unroll
            for (int qq = 0; qq < 4; ++qq) acc[fi][fj][qq] += rsv[fi][qq];

    float* Sb = S + (size_t)bz * N * N;
#pragma unroll
    for (int fi = 0; fi < 4; ++fi) {
        int rg = n0 + wr * 64 + fi * 16 + h * 4;
#pragma unroll
        for (int fj = 0; fj < 4; ++fj) {
            int cg = j0 + wc * 64 + fj * 16 + r;
            if (cg < N) {
#pragma unroll
                for (int qq = 0; qq < 4; ++qq)
                    if (rg + qq < N) Sb[(size_t)(rg + qq) * N + cg] = acc[fi][fj][qq];
            }
        }
    }

    // per-column max and sum(exp(v-max)) over this block's 128 rows
#pragma unroll
    for (int fj = 0; fj < 4; ++fj) {
        float m = -3.0e38f;
#pragma unroll
        for (int fi = 0; fi < 4; ++fi)
#pragma unroll
            for (int qq = 0; qq < 4; ++qq) {
                int rg = n0 + wr * 64 + fi * 16 + h * 4 + qq;
                float v = (rg < N) ? acc[fi][fj][qq] : -3.0e38f;
                m = fmaxf(m, v);
            }
        m = fmaxf(m, __shfl_xor(m, 16));
        m = fmaxf(m, __shfl_xor(m, 32));
        float s = 0.f;
#pragma unroll
        for (int fi = 0; fi < 4; ++fi)
#pragma unroll
            for (int qq = 0; qq < 4; ++qq) {
                int rg = n0 + wr * 64 + fi * 16 + h * 4 + qq;
                if (rg < N) s += __expf(acc[fi][fj][qq] - m);
            }
        s += __shfl_xor(s, 16);
        s += __shfl_xor(s, 32);
        if (lane < 16) {
            smx[wr][wc][fj * 16 + lane] = m;
            ssm[wr][wc][fj * 16 + lane] = s;
        }
    }
    __syncthreads();
    if (tid < 128) {
        int wcc = tid >> 6, c = tid & 63;
        float m0 = smx[0][wcc][c], m1 = smx[1][wcc][c];
        float m = fmaxf(m0, m1);
        float s = ssm[0][wcc][c] * __expf(m0 - m) + ssm[1][wcc][c] * __expf(m1 - m);
        int j = j0 + wcc * 64 + c;
        size_t o = ((size_t)bz * 6 + nt) * 768 + j;
        pmax[o] = m;
        psum[o] = s;
    }
}

// ---------------- K5: fused combine + normalize -------------------------------
// grid (12 j-strips of 64, B). Phase 1: threads 0..63 combine the 6 row-tile
// partials for their j into LDS. Phase 2: stream this (b, :, j-strip) of S in
// place (float4; 716 divisible by 4).
__global__ void __launch_bounds__(256) k_norm3(float* __restrict__ S,
                                               const float* __restrict__ pmax,
                                               const float* __restrict__ psum) {
    __shared__ float smaxL[64];
    __shared__ float sinvL[64];
    int jt = blockIdx.x, b = blockIdx.y;
    int j0 = jt * 64;
    int tid = threadIdx.x;
    if (tid < 64) {
        int j = j0 + tid;
        float m = -3.0e38f, s = 0.f;
        if (j < N) {
#pragma unroll
            for (int c = 0; c < 6; ++c) m = fmaxf(m, pmax[((size_t)b * 6 + c) * 768 + j]);
#pragma unroll
            for (int c = 0; c < 6; ++c)
                s += psum[((size_t)b * 6 + c) * 768 + j] * __expf(pmax[((size_t)b * 6 + c) * 768 + j] - m);
        } else {
            s = 1.f;
        }
        smaxL[tid] = m;
        sinvL[tid] = 1.f / s;
    }
    __syncthreads();

    int rowo = tid >> 4;          // 0..15
    int q = tid & 15;             // 0..15 -> j offset q*4
    int jj = q * 4;
    if (j0 + jj >= N) return;     // strip tail (jt=11: only q<3 valid)
    float m0 = smaxL[jj], m1 = smaxL[jj + 1], m2 = smaxL[jj + 2], m3 = smaxL[jj + 3];
    float r0 = sinvL[jj], r1 = sinvL[jj + 1], r2 = sinvL[jj + 2], r3 = sinvL[jj + 3];
    float* Sb = S + (size_t)b * N * N + j0 + jj;
    for (int r = rowo; r < N; r += 16) {
        float4 v = *(float4*)(Sb + (size_t)r * N);
        v.x = __expf(v.x - m0) * r0;
        v.y = __expf(v.y - m1) * r1;
        v.z = __expf(v.z - m2) * r2;
        v.w = __expf(v.w - m3) * r3;
        *(float4*)(Sb + (size_t)r * N) = v;
    }
}

extern "C" void kernel_launch(void* const* d_in, const int* in_sizes, int n_in,
                              void* d_out, int out_size, void* d_ws, size_t ws_size,
                              hipStream_t stream) {
    const float* vals   = (const float*)d_in[0];  // [B,T,E]
    const float* W_flat = (const float*)d_in[1];  // [C,E]
    const float* bias   = (const float*)d_in[2];  // [N,C]
    const float* W1     = (const float*)d_in[3];  // [T]
    const float* W2     = (const float*)d_in[4];  // [C,T]
    const float* W3     = (const float*)d_in[5];  // [C]
    const float* bs     = (const float*)d_in[6];  // [1,N,N]
    const float* Vs     = (const float*)d_in[7];  // [N,N]
    float* out = (float*)d_out;                   // [B,N,N]

    float* f = (float*)d_ws;
    f16* sigT = (f16*)f;   f += (size_t)B * N * KP / 2;     // 17,596,416 floats
    f16* AHp  = (f16*)f;   f += (size_t)N * KP / 2;         // 274,944
    f16* ALp  = (f16*)f;   f += (size_t)N * KP / 2;
    float* rhs  = f;  f += (size_t)B * N * T;               // 549,888
    float* lhs  = f;  f += (size_t)B * N * T;
    float* bsT  = f;  f += (size_t)N * N;                   // 512,656
    float* rsw  = f;  f += 720;
    float* pmax = f;  f += (size_t)B * 6 * 768;             // 294,912
    float* psum = f;  f += (size_t)B * 6 * 768;

    k_static<<<KB_PLANES + KB_BST + KB_RS, 256, 0, stream>>>(Vs, bs, AHp, ALp, bsT, rsw);

    k_fused_ln<<<(B * N) / 4, 256, 0, stream>>>(vals, W_flat, bias, W1, W2, W3, rhs, lhs);

    dim3 gp(3, (N + 15) / 16, B);
    k_prod2<<<gp, 256, 0, stream>>>(lhs, rhs, bsT, sigT);

    dim3 gg((N + 127) / 128, (N + 127) / 128, B);
    k_mfma<<<gg, 256, 0, stream>>>(AHp, ALp, sigT, rsw, out, pmax, psum);

    k_norm3<<<dim3(12, B), 256, 0, stream>>>(out, pmax, psum);
}